// Round 2
// baseline (272.406 us; speedup 1.0000x reference)
//
#include <hip/hip_runtime.h>

#define BATCH 2048
#define VOCAB 256
#define KDIM 16384
#define BM 32
#define BK 32
#define KCHUNK 1024
#define NT (KCHUNK / BK)     // 32 K-steps per chunk
#define NKCH (KDIM / KCHUNK) // 16 K-chunks (grid.y)
#define LN10 2.302585092994046f

typedef __attribute__((ext_vector_type(8))) short short8;
typedef __attribute__((ext_vector_type(4))) float f32x4;

__device__ __forceinline__ unsigned short f2bf_rne(float f) {
  unsigned int u = __float_as_uint(f);
  u += 0x7fffu + ((u >> 16) & 1u);
  return (unsigned short)(u >> 16);
}
// binary values are exactly 0.0f/1.0f -> truncation is exact
__device__ __forceinline__ unsigned int pack2(float lo, float hi) {
  return (__float_as_uint(lo) >> 16) | (__float_as_uint(hi) & 0xffff0000u);
}

__device__ __forceinline__ void async16(void* lds, const void* g) {
  __builtin_amdgcn_global_load_lds(
      (const __attribute__((address_space(1))) unsigned int*)g,
      (__attribute__((address_space(3))) unsigned int*)lds, 16, 0, 0);
}

// ---------------- log_w precompute: logw = bf16(log(10*sigmoid(raw))) -------
__global__ __launch_bounds__(256) void k_logw(const float* __restrict__ raw,
                                              unsigned short* __restrict__ logw) {
  int i = blockIdx.x * 256 + threadIdx.x; // float4 index, exact grid
  float4 x = ((const float4*)raw)[i];
  ushort4 r;
  r.x = f2bf_rne(LN10 - log1pf(expf(-x.x)));
  r.y = f2bf_rne(LN10 - log1pf(expf(-x.y)));
  r.z = f2bf_rne(LN10 - log1pf(expf(-x.z)));
  r.w = f2bf_rne(LN10 - log1pf(expf(-x.w)));
  ((ushort4*)logw)[i] = r;
}

// ---------------- main K-split MFMA GEMM ------------------------------------
// grid (64, 16) = 1024 blocks = exactly 4/CU resident. 256 threads (4 waves).
// Static LDS 36 KB: A[2][32][64B], B[2][256][64B], rows 64 B bf16.
// Swizzle: phys_byte(row, k16slot) = row*64 + ((slot ^ (row&3))*16)
__global__ __launch_bounds__(256, 4) void k_gemm(
    const float* __restrict__ binary, const unsigned short* __restrict__ logw,
    float* __restrict__ accb, float* __restrict__ nact) {
  __shared__ char smem[36864];
  char* const Ab0 = smem;
  char* const Ab1 = smem + 2048;
  char* const Bb0 = smem + 4096;
  char* const Bb1 = smem + 20480;

  const int tid = threadIdx.x;
  const int wv = tid >> 6;
  const int lane = tid & 63;
  const int l15 = lane & 15;
  const int lhi = lane >> 4;
  const int m0 = blockIdx.x * BM;
  const int k0 = blockIdx.y * KCHUNK;

  // A staging: thread -> row ar (8 thr/row), fp32 float4 chunk ac
  const int ar = tid >> 3, ac = tid & 7;
  const float* a_src = binary + (size_t)(m0 + ar) * KDIM + k0 + ac * 4;
  const int aw = ar * 64 + ((((ac >> 1) ^ (ar & 3)) << 4) | ((ac & 1) << 3));

  // B staging via global_load_lds: linear LDS dest, pre-swizzled global src.
  // instr i: lane -> row wv*64 + i*16 + (lane>>2); fetch logical slot bs
  const int br = lane >> 2;
  const int bs = (lane & 3) ^ (br & 3);
  const unsigned short* b_src =
      logw + (size_t)(wv * 64 + br) * KDIM + k0 + bs * 8;

  float4 areg;
  float asum = 0.f;
  f32x4 acc[2][4];
#pragma unroll
  for (int m = 0; m < 2; ++m)
#pragma unroll
    for (int n = 0; n < 4; ++n) acc[m][n] = f32x4{0.f, 0.f, 0.f, 0.f};

  auto A_LOAD = [&](int t) { areg = *(const float4*)(a_src + t * BK); };
  auto A_WRITE = [&](char* A) {
    asum += areg.x + areg.y + areg.z + areg.w;
    uint2 u;
    u.x = pack2(areg.x, areg.y);
    u.y = pack2(areg.z, areg.w);
    *(uint2*)(A + aw) = u;
  };
  auto B_STAGE = [&](int t, char* B) {
#pragma unroll
    for (int i = 0; i < 4; ++i)
      async16(B + wv * 4096 + i * 1024, b_src + (size_t)i * 16 * KDIM + t * BK);
  };
  auto COMPUTE = [&](const char* A, const char* B) {
    const int sw = (lhi ^ (l15 & 3)) << 4;
    short8 af[2], bfr[4];
    af[0] = *(const short8*)(A + l15 * 64 + sw);
    af[1] = *(const short8*)(A + (16 + l15) * 64 + sw);
#pragma unroll
    for (int n = 0; n < 4; ++n)
      bfr[n] = *(const short8*)(B + (wv * 64 + n * 16 + l15) * 64 + sw);
#pragma unroll
    for (int m = 0; m < 2; ++m)
#pragma unroll
      for (int n = 0; n < 4; ++n)
        acc[m][n] = __builtin_amdgcn_mfma_f32_16x16x32_bf16(af[m], bfr[n],
                                                            acc[m][n], 0, 0, 0);
  };

  // prologue: stage tile 0 into buffer 0
  A_LOAD(0);
  B_STAGE(0, Bb0);
  A_WRITE(Ab0);
  __syncthreads();

  // statically 2-unrolled double-buffer loop (no runtime-indexed buffers)
#pragma unroll 1
  for (int t = 0; t < NT; t += 2) {
    // even step: compute buf0, stage t+1 into buf1  (t+1 <= 31 always valid)
    A_LOAD(t + 1);
    B_STAGE(t + 1, Bb1);
    COMPUTE(Ab0, Bb0);
    A_WRITE(Ab1);
    __syncthreads();
    // odd step: compute buf1, stage t+2 into buf0
    if (t + 2 < NT) {
      A_LOAD(t + 2);
      B_STAGE(t + 2, Bb0);
    }
    COMPUTE(Ab1, Bb1);
    if (t + 2 < NT) A_WRITE(Ab0);
    __syncthreads();
  }

  // n_active partial: 8 consecutive lanes share one A row
  float s = asum;
  s += __shfl_xor(s, 1, 64);
  s += __shfl_xor(s, 2, 64);
  s += __shfl_xor(s, 4, 64);
  if ((lane & 7) == 0) atomicAdd(&nact[m0 + (tid >> 3)], s);

  // K-split reduction: fp32 atomics. C/D layout: col=lane&15, row=lhi*4+i
#pragma unroll
  for (int m = 0; m < 2; ++m)
#pragma unroll
    for (int n = 0; n < 4; ++n)
#pragma unroll
      for (int i = 0; i < 4; ++i) {
        int r = m0 + m * 16 + lhi * 4 + i;
        int c = wv * 64 + n * 16 + l15;
        atomicAdd(&accb[(size_t)r * VOCAB + c], acc[m][n][i]);
      }
}

// ---------------- epilogue: logits = exp(log_sum / max(n_active,1)) ---------
__global__ __launch_bounds__(256) void k_out(float* __restrict__ io,
                                             const float* __restrict__ nact) {
  int b = blockIdx.x;
  int v = threadIdx.x;
  float n = fmaxf(nact[b], 1.0f);
  size_t idx = (size_t)b * VOCAB + v;
  io[idx] = expf(io[idx] / n);
}

extern "C" void kernel_launch(void* const* d_in, const int* in_sizes, int n_in,
                              void* d_out, int out_size, void* d_ws, size_t ws_size,
                              hipStream_t stream) {
  const float* binary = (const float*)d_in[0];
  const float* raw = (const float*)d_in[1];
  float* out = (float*)d_out;
  char* ws = (char*)d_ws;
  unsigned short* logw = (unsigned short*)ws;             // 8 MB
  float* nact = (float*)(ws + (size_t)8 * 1024 * 1024);   // 8 KB

  hipMemsetAsync(out, 0, (size_t)BATCH * VOCAB * sizeof(float), stream);
  hipMemsetAsync(nact, 0, BATCH * sizeof(float), stream);

  k_logw<<<(VOCAB * KDIM / 4) / 256, 256, 0, stream>>>(raw, logw);

  dim3 g(BATCH / BM, NKCH);
  k_gemm<<<g, 256, 0, stream>>>(binary, logw, out, nact);

  k_out<<<BATCH, VOCAB, 0, stream>>>(out, nact);
}